// Round 17
// baseline (95.789 us; speedup 1.0000x reference)
//
#include <hip/hip_runtime.h>
#include <stdint.h>

using bf16x8 = __attribute__((ext_vector_type(8))) short;
using f32x4  = __attribute__((ext_vector_type(4))) float;

#define DEVINL __device__ __forceinline__

DEVINL unsigned short f2bf(float f) {
  union { float f; unsigned u; } v; v.f = f;
  unsigned u = v.u;
  return (unsigned short)((u + 0x7FFFu + ((u >> 16) & 1u)) >> 16);
}
DEVINL float bf2f(unsigned short h) {
  union { unsigned u; float f; } v; v.u = ((unsigned)h) << 16;
  return v.f;
}

DEVINL void gload_lds16(const void* g, void* l) {
  __builtin_amdgcn_global_load_lds(
      (const __attribute__((address_space(1))) void*)g,
      (__attribute__((address_space(3))) void*)l, 16, 0, 0);
}

// ---------------------------------------------------------------------------
// core256 (m201 geometry): 256x256 bf16 tile, 8 waves 2M x 4N (per-wave
// 128x64 out, acc 8x4), BK=64, 2 LDS buffers (128 KB). Per K-tile 4 phases:
//   ph1 {A-reads rh=0 kk=0 + B-reads kk=0 ; STAGE-A(kt+1) ; bar ; 16 MFMA ; bar}
//   ph2 {A-reads rh=1 kk=0              ; STAGE-B(kt+1) ; bar ; 16 MFMA ; bar}
//   ph3 {A-reads rh=0 kk=32 + B kk=32   ;               ; bar ; 16 MFMA ; bar}
//   ph4 {A-reads rh=1 kk=32 ; vmcnt(0) [kt+1, issued >=2 phases ago] ; bar ;
//        16 MFMA ; bar}
// T2 XOR swizzle via pre-swizzled GLOBAL source (LDS dest linear, rule 21;
// conflicts measured 0 in r8/r12/r15). setprio(1) around MFMA clusters (T5).
// Buffer hazard: stage(kt+1)->buf (kt+1)&1, last read at tile kt-1's trailing
// barrier. Output always bf16, no bias. kofs = split-K column offset.
// ---------------------------------------------------------------------------
DEVINL void gemm_core256(const unsigned short* __restrict__ A,
                         const unsigned short* __restrict__ B,
                         unsigned short* __restrict__ C,
                         int Klen, int ld, int Cld,
                         int arow0, int brow0, int crow0, int ccol0, int kofs)
{
  __shared__ __align__(16) unsigned short As[2][256 * 64];   // 64 KB
  __shared__ __align__(16) unsigned short Bs[2][256 * 64];   // 64 KB

  const int t    = threadIdx.x;        // 0..511
  const int wave = t >> 6;             // 0..7
  const int lane = t & 63;
  const int wr   = (wave >> 2) << 7;   // 0,128
  const int wc   = (wave & 3) << 6;    // 0,64,128,192
  const int lrow = lane & 15;
  const int kg   = lane >> 4;          // 0..3

  f32x4 acc[8][4];
#pragma unroll
  for (int r = 0; r < 8; ++r)
#pragma unroll
    for (int q = 0; q < 4; ++q) acc[r][q] = (f32x4){0.f, 0.f, 0.f, 0.f};

  // staging (pre-swizzled global source chunk: chunk_phys = chunk ^ (row&7);
  // pass stride 64 rows keeps row&7 invariant)
  const int srow = t >> 3;                                  // 0..63
  const int scol = (((t & 7) ^ (srow & 7)) << 3);
  const unsigned short* aSrc = A + (size_t)(arow0 + srow) * ld + kofs + scol;
  const unsigned short* bSrc = B + (size_t)(brow0 + srow) * ld + kofs + scol;

  auto STAGE_A = [&](int buf, int kt) {
    const int k0 = kt << 6;
    char* aD = (char*)As[buf] + wave * 1024;
#pragma unroll
    for (int p = 0; p < 4; ++p)
      gload_lds16(aSrc + (size_t)(p * 64) * ld + k0, aD + p * 8192);
  };
  auto STAGE_B = [&](int buf, int kt) {
    const int k0 = kt << 6;
    char* bD = (char*)Bs[buf] + wave * 1024;
#pragma unroll
    for (int p = 0; p < 4; ++p)
      gload_lds16(bSrc + (size_t)(p * 64) * ld + k0, bD + p * 8192);
  };

  const int nt = Klen >> 6;
  STAGE_A(0, 0); STAGE_B(0, 0);
  asm volatile("s_waitcnt vmcnt(0)" ::: "memory");
  __builtin_amdgcn_s_barrier();

  // swizzled read chunk offsets: chunk = (kg + kk/8) ^ (row&7)
  const int rs = lrow & 7;
  const int cA0 = ((kg + 0) ^ rs) << 3;   // kk = 0
  const int cA1 = ((kg + 4) ^ rs) << 3;   // kk = 32

  bf16x8 a[4], b[4];
  for (int kt = 0; kt < nt; ++kt) {
    const unsigned short* Ab = As[kt & 1];
    const unsigned short* Bb = Bs[kt & 1];
    const int nbuf = (kt + 1) & 1;

    // ---- phase 1: A rh=0 kk=0 + B kk=0 ; stage A(kt+1)
#pragma unroll
    for (int r = 0; r < 4; ++r)
      a[r] = *(const bf16x8*)&Ab[(wr + r * 16 + lrow) * 64 + cA0];
#pragma unroll
    for (int q = 0; q < 4; ++q)
      b[q] = *(const bf16x8*)&Bb[(wc + q * 16 + lrow) * 64 + cA0];
    if (kt + 1 < nt) STAGE_A(nbuf, kt + 1);
    __builtin_amdgcn_s_barrier();
    __builtin_amdgcn_s_setprio(1);
#pragma unroll
    for (int r = 0; r < 4; ++r)
#pragma unroll
      for (int q = 0; q < 4; ++q)
        acc[r][q] = __builtin_amdgcn_mfma_f32_16x16x32_bf16(a[r], b[q], acc[r][q], 0, 0, 0);
    __builtin_amdgcn_s_setprio(0);
    __builtin_amdgcn_s_barrier();

    // ---- phase 2: A rh=1 kk=0 (B reused) ; stage B(kt+1)
#pragma unroll
    for (int r = 0; r < 4; ++r)
      a[r] = *(const bf16x8*)&Ab[(wr + 64 + r * 16 + lrow) * 64 + cA0];
    if (kt + 1 < nt) STAGE_B(nbuf, kt + 1);
    __builtin_amdgcn_s_barrier();
    __builtin_amdgcn_s_setprio(1);
#pragma unroll
    for (int r = 0; r < 4; ++r)
#pragma unroll
      for (int q = 0; q < 4; ++q)
        acc[4 + r][q] = __builtin_amdgcn_mfma_f32_16x16x32_bf16(a[r], b[q], acc[4 + r][q], 0, 0, 0);
    __builtin_amdgcn_s_setprio(0);
    __builtin_amdgcn_s_barrier();

    // ---- phase 3: A rh=0 kk=32 + B kk=32
#pragma unroll
    for (int r = 0; r < 4; ++r)
      a[r] = *(const bf16x8*)&Ab[(wr + r * 16 + lrow) * 64 + cA1];
#pragma unroll
    for (int q = 0; q < 4; ++q)
      b[q] = *(const bf16x8*)&Bb[(wc + q * 16 + lrow) * 64 + cA1];
    __builtin_amdgcn_s_barrier();
    __builtin_amdgcn_s_setprio(1);
#pragma unroll
    for (int r = 0; r < 4; ++r)
#pragma unroll
      for (int q = 0; q < 4; ++q)
        acc[r][q] = __builtin_amdgcn_mfma_f32_16x16x32_bf16(a[r], b[q], acc[r][q], 0, 0, 0);
    __builtin_amdgcn_s_setprio(0);
    __builtin_amdgcn_s_barrier();

    // ---- phase 4: A rh=1 kk=32 ; validate kt+1 (issued >=2 phases ago)
#pragma unroll
    for (int r = 0; r < 4; ++r)
      a[r] = *(const bf16x8*)&Ab[(wr + 64 + r * 16 + lrow) * 64 + cA1];
    if (kt + 1 < nt)
      asm volatile("s_waitcnt vmcnt(0)" ::: "memory");
    __builtin_amdgcn_s_barrier();
    __builtin_amdgcn_s_setprio(1);
#pragma unroll
    for (int r = 0; r < 4; ++r)
#pragma unroll
      for (int q = 0; q < 4; ++q)
        acc[4 + r][q] = __builtin_amdgcn_mfma_f32_16x16x32_bf16(a[r], b[q], acc[4 + r][q], 0, 0, 0);
    __builtin_amdgcn_s_setprio(0);
    __builtin_amdgcn_s_barrier();
  }

  // epilogue: C/D layout col=lane&15, row=(lane>>4)*4+v  [m89/m91 verified]
#pragma unroll
  for (int rr = 0; rr < 8; ++rr) {
#pragma unroll
    for (int q = 0; q < 4; ++q) {
      const int col = ccol0 + wc + q * 16 + lrow;
      const int rowb = crow0 + wr + (rr >> 2) * 64 + (rr & 3) * 16 + (kg << 2);
#pragma unroll
      for (int v = 0; v < 4; ++v)
        C[(size_t)(rowb + v) * Cld + col] = f2bf(acc[rr][q][v]);
    }
  }
}

// ---------------------------------------------------------------------------
// r15 core (proven) — used by gemmF only: 256x128, 8 waves 4M x 2N, 3-slot
// ring, 2 phases/K-tile, counted vmcnt(6).
// ---------------------------------------------------------------------------
template<int OUT_BF16, int HAS_BIAS>
DEVINL void gemm_core(const unsigned short* __restrict__ A,
                      const unsigned short* __restrict__ B,
                      void* __restrict__ C,
                      const float* __restrict__ bias,
                      int K, int Cld, int arow0, int brow0, int crow0, int ccol0)
{
  __shared__ __align__(16) unsigned short As[3][256 * 64];
  __shared__ __align__(16) unsigned short Bs[3][128 * 64];

  const int t    = threadIdx.x;
  const int wave = t >> 6;
  const int lane = t & 63;
  const int wr   = (wave >> 1) << 6;
  const int wc   = (wave & 1) << 6;
  const int lrow = lane & 15;
  const int kg   = lane >> 4;

  f32x4 acc[4][4];
#pragma unroll
  for (int r = 0; r < 4; ++r)
#pragma unroll
    for (int q = 0; q < 4; ++q) acc[r][q] = (f32x4){0.f, 0.f, 0.f, 0.f};

  const int srow = t >> 3;
  const int scol = (((t & 7) ^ (srow & 7)) << 3);
  const unsigned short* aSrc = A + (size_t)(arow0 + srow) * K + scol;
  const unsigned short* bSrc = B + (size_t)(brow0 + srow) * K + scol;

  auto STAGE_S0 = [&](int slot, int kt) {
    const int k0 = kt << 6;
    char* aD = (char*)As[slot] + wave * 1024;
    char* bD = (char*)Bs[slot] + wave * 1024;
    gload_lds16(aSrc + (size_t)0 * K + k0, aD);
    gload_lds16(aSrc + (size_t)64 * K + k0, aD + 8192);
    gload_lds16(bSrc + (size_t)0 * K + k0, bD);
  };
  auto STAGE_S1 = [&](int slot, int kt) {
    const int k0 = kt << 6;
    char* aD = (char*)As[slot] + wave * 1024;
    char* bD = (char*)Bs[slot] + wave * 1024;
    gload_lds16(aSrc + (size_t)128 * K + k0, aD + 16384);
    gload_lds16(aSrc + (size_t)192 * K + k0, aD + 24576);
    gload_lds16(bSrc + (size_t)64 * K + k0, bD + 8192);
  };

  const int nt = K >> 6;
  STAGE_S0(0, 0); STAGE_S1(0, 0);
  if (nt > 1) { STAGE_S0(1, 1); STAGE_S1(1, 1); }

  const int rs = lrow & 7;
  const int cA0 = ((kg + 0) ^ rs) << 3;
  const int cA1 = ((kg + 4) ^ rs) << 3;

  if (nt > 1) { asm volatile("s_waitcnt vmcnt(6)" ::: "memory"); }
  else        { asm volatile("s_waitcnt vmcnt(0)" ::: "memory"); }
  __builtin_amdgcn_s_barrier();

  int sl = 0;
  for (int kt = 0; kt < nt; ++kt) {
    const unsigned short* Ab = As[sl];
    const unsigned short* Bb = Bs[sl];
    int s2 = sl + 2; if (s2 >= 3) s2 -= 3;

    bf16x8 af[4], bq[4];
#pragma unroll
    for (int r = 0; r < 4; ++r)
      af[r] = *(const bf16x8*)&Ab[(wr + r * 16 + lrow) * 64 + cA0];
#pragma unroll
    for (int q = 0; q < 4; ++q)
      bq[q] = *(const bf16x8*)&Bb[(wc + q * 16 + lrow) * 64 + cA0];
    if (kt + 2 < nt) STAGE_S0(s2, kt + 2);
    __builtin_amdgcn_s_barrier();
    __builtin_amdgcn_s_setprio(1);
#pragma unroll
    for (int r = 0; r < 4; ++r)
#pragma unroll
      for (int q = 0; q < 4; ++q)
        acc[r][q] = __builtin_amdgcn_mfma_f32_16x16x32_bf16(af[r], bq[q], acc[r][q], 0, 0, 0);
    __builtin_amdgcn_s_setprio(0);
    __builtin_amdgcn_s_barrier();

#pragma unroll
    for (int r = 0; r < 4; ++r)
      af[r] = *(const bf16x8*)&Ab[(wr + r * 16 + lrow) * 64 + cA1];
#pragma unroll
    for (int q = 0; q < 4; ++q)
      bq[q] = *(const bf16x8*)&Bb[(wc + q * 16 + lrow) * 64 + cA1];
    if (kt + 2 < nt) {
      STAGE_S1(s2, kt + 2);
      asm volatile("s_waitcnt vmcnt(6)" ::: "memory");
    } else if (kt + 1 < nt) {
      asm volatile("s_waitcnt vmcnt(0)" ::: "memory");
    }
    __builtin_amdgcn_s_barrier();
    __builtin_amdgcn_s_setprio(1);
#pragma unroll
    for (int r = 0; r < 4; ++r)
#pragma unroll
      for (int q = 0; q < 4; ++q)
        acc[r][q] = __builtin_amdgcn_mfma_f32_16x16x32_bf16(af[r], bq[q], acc[r][q], 0, 0, 0);
    __builtin_amdgcn_s_setprio(0);
    __builtin_amdgcn_s_barrier();

    ++sl; if (sl == 3) sl = 0;
  }

#pragma unroll
  for (int r = 0; r < 4; ++r) {
#pragma unroll
    for (int q = 0; q < 4; ++q) {
      const int col = ccol0 + wc + q * 16 + lrow;
      const float bv = HAS_BIAS ? bias[col] : 0.f;
#pragma unroll
      for (int v = 0; v < 4; ++v) {
        const int row = crow0 + wr + r * 16 + (kg << 2) + v;
        const float val = acc[r][q][v] + bv;
        if (OUT_BF16)
          ((unsigned short*)C)[(size_t)row * Cld + col] = f2bf(val);
        else
          ((float*)C)[(size_t)row * Cld + col] = val;
      }
    }
  }
}

// ---------------------------------------------------------------------------
// mega1 (208 blocks x 512 thr), 256x256 core + split-K x2:
//  bids 0..159  -> H0h[kh][p] partial = XR[m(p)][kh]·w1cat[j(p)][kh]^T
//                  (20 p x {kh,rt,ct} of 2x2x2)
//  bids 160..207 -> W2ENh[kh][s] partial (4 s x {kh, rt(3), ct(2)})
// ---------------------------------------------------------------------------
__global__ __launch_bounds__(512) void mega1_k(const unsigned short* __restrict__ xrb,
                                               const unsigned short* __restrict__ w1cat,
                                               const unsigned short* __restrict__ wen,
                                               const unsigned short* __restrict__ w2t,
                                               unsigned short* __restrict__ H0h,
                                               unsigned short* __restrict__ W2ENh) {
  const int bid = blockIdx.x;
  if (bid < 160) {
    const int p = bid >> 3, rem = bid & 7;
    const int kh = rem & 1, rt = (rem >> 1) & 1, ct = rem >> 2;
    const int MM[20] = {0,1,2,3, 0,1,2, 1,2,3, 0,1, 1,2, 2,3, 0,1,2,3};
    const int JJ[20] = {0,0,0,0, 1,1,1, 2,2,2, 3,3, 4,4, 5,5, 6,7,8,9};
    gemm_core256(xrb, w1cat, H0h + (size_t)kh * 5242880, 1024, 2048, 512,
                 MM[p] * 512 + rt * 256, JJ[p] * 512 + ct * 256,
                 p * 512 + rt * 256, ct * 256, kh * 1024);
  } else {
    const int b2 = bid - 160;
    const int s = b2 / 12, r = b2 % 12;
    const int kh = r & 1, tt = r >> 1;        // tt 0..5
    const int rt = tt >> 1, ct = tt & 1;      // rt 0..2, ct 0..1
    gemm_core256(wen, w2t, W2ENh + (size_t)kh * 1572864, 1024, 2048, 512,
                 rt * 256, s * 512 + ct * 256,
                 s * 768 + rt * 256, ct * 256, kh * 1024);
  }
}

// gemmF: EN0 = h1(7680x512) @ W2EN_s^T + ENb_s   (fp32 out, 768 cols)
__global__ __launch_bounds__(512) void gemmF_k(const unsigned short* __restrict__ h1,
                                               const unsigned short* __restrict__ W2EN,
                                               const float* __restrict__ ENb,
                                               float* __restrict__ EN0) {
  const int y = blockIdx.y;                  // 0..29 row tiles of 256
  const int c = y >> 1;
  const int s = (c < 4) ? 1 : (c < 10) ? 2 : (c < 14) ? 3 : 4;
  gemm_core<0, 1>(h1, W2EN, EN0, ENb + (size_t)(s - 1) * 768, 512, 768,
                  y * 256, (s - 1) * 768 + blockIdx.x * 128,
                  y * 256, blockIdx.x * 128);
}

// ---------------------------------------------------------------------------
// prep_all (r13 proven): 5 prep bodies in one dispatch (17664 blocks).
// ---------------------------------------------------------------------------
__global__ __launch_bounds__(256) void prep_all_k(const float* __restrict__ x,
                                                  const float* w11, const float* w12,
                                                  const float* w13, const float* w14,
                                                  const float* w21, const float* w22,
                                                  const float* w23, const float* w24,
                                                  const float* __restrict__ wemb,
                                                  const float* __restrict__ wnode,
                                                  const float* b21, const float* b22,
                                                  const float* b23, const float* b24,
                                                  unsigned short* __restrict__ xrb,
                                                  unsigned short* __restrict__ w1cat,
                                                  unsigned short* __restrict__ w2t,
                                                  unsigned short* __restrict__ wen,
                                                  float* __restrict__ ENb) {
  __shared__ float lds[64][65];
  __shared__ float red[4][4];
  const int bid = blockIdx.x;
  if (bid < 10240) {                    // ---- w1cat
    const int tid = bid * 256 + threadIdx.x;
    const int r = tid >> 9;
    const int k = (tid & 511) << 2;
    const int j = r >> 9, o = r & 511;
    const float* src; int s, tt;
    if (j == 0)      { src = w11; s = 1; tt = 0; }
    else if (j < 3)  { src = w12; s = 2; tt = j - 1; }
    else if (j < 6)  { src = w13; s = 3; tt = j - 3; }
    else             { src = w14; s = 4; tt = j - 6; }
    const float4 vv = *(const float4*)(src + (size_t)o * (s * 2048) + tt * 2048 + k);
    ushort4 ov;
    ov.x = f2bf(vv.x); ov.y = f2bf(vv.y); ov.z = f2bf(vv.z); ov.w = f2bf(vv.w);
    *(ushort4*)(w1cat + (size_t)r * 2048 + k) = ov;
  } else if (bid < 14336) {             // ---- xr
    const int tid = (bid - 10240) * 256 + threadIdx.x;
    const int r = tid >> 9;
    const int k = (tid & 511) << 2;
    const int m = r >> 9, b = r & 511;
    const float4 vv = *(const float4*)(x + ((size_t)(b * 4 + m)) * 2048 + k);
    ushort4 o;
    o.x = f2bf(fmaxf(vv.x, 0.f)); o.y = f2bf(fmaxf(vv.y, 0.f));
    o.z = f2bf(fmaxf(vv.z, 0.f)); o.w = f2bf(fmaxf(vv.w, 0.f));
    *(ushort4*)(xrb + (size_t)r * 2048 + k) = o;
  } else if (bid < 15360) {             // ---- w2t
    const int idx = bid - 14336;
    const int s = idx >> 8, rem = idx & 255;
    const int rt = rem >> 3, ct = rem & 7;
    const float* src = (s == 0) ? w21 : (s == 1) ? w22 : (s == 2) ? w23 : w24;
    const int tr = threadIdx.x >> 4;
    const int tc = (threadIdx.x & 15) << 2;
#pragma unroll
    for (int i = 0; i < 4; ++i) {
      const float4 v = *(const float4*)(src + (size_t)(rt * 64 + tr + 16 * i) * 512 + ct * 64 + tc);
      lds[tr + 16 * i][tc + 0] = v.x; lds[tr + 16 * i][tc + 1] = v.y;
      lds[tr + 16 * i][tc + 2] = v.z; lds[tr + 16 * i][tc + 3] = v.w;
    }
    __syncthreads();
#pragma unroll
    for (int i = 0; i < 4; ++i) {
      ushort4 ov;
      ov.x = f2bf(lds[tc + 0][tr + 16 * i]); ov.y = f2bf(lds[tc + 1][tr + 16 * i]);
      ov.z = f2bf(lds[tc + 2][tr + 16 * i]); ov.w = f2bf(lds[tc + 3][tr + 16 * i]);
      *(ushort4*)(w2t + ((size_t)s * 512 + ct * 64 + tr + 16 * i) * 2048 + rt * 64 + tc) = ov;
    }
  } else if (bid < 16896) {             // ---- wen
    const int tid = (bid - 15360) * 256 + threadIdx.x;
    const int r = tid >> 9;
    const int k = (tid & 511) << 2;
    float4 vv = make_float4(0.f, 0.f, 0.f, 0.f);
    if (r < 300)       vv = *(const float4*)(wemb + (size_t)r * 2048 + k);
    else if (r < 691)  vv = *(const float4*)(wnode + (size_t)(r - 300) * 2048 + k);
    ushort4 ov;
    ov.x = f2bf(vv.x); ov.y = f2bf(vv.y); ov.z = f2bf(vv.z); ov.w = f2bf(vv.w);
    *(ushort4*)(wen + (size_t)r * 2048 + k) = ov;
  } else {                              // ---- enb v2
    const int e = bid - 16896;          // 0..767
    const int t8 = threadIdx.x << 3;
    float a0 = 0.f, a1 = 0.f, a2 = 0.f, a3 = 0.f;
    if (e < 691) {
      const float* row = (e < 300) ? (wemb + (size_t)e * 2048)
                                   : (wnode + (size_t)(e - 300) * 2048);
      const float4 r0 = *(const float4*)(row + t8);
      const float4 r1 = *(const float4*)(row + t8 + 4);
      const float4 c10 = *(const float4*)(b21 + t8), c11 = *(const float4*)(b21 + t8 + 4);
      const float4 c20 = *(const float4*)(b22 + t8), c21 = *(const float4*)(b22 + t8 + 4);
      const float4 c30 = *(const float4*)(b23 + t8), c31 = *(const float4*)(b23 + t8 + 4);
      const float4 c40 = *(const float4*)(b24 + t8), c41 = *(const float4*)(b24 + t8 + 4);
      a0 = r0.x*c10.x + r0.y*c10.y + r0.z*c10.z + r0.w*c10.w
         + r1.x*c11.x + r1.y*c11.y + r1.z*c11.z + r1.w*c11.w;
      a1 = r0.x*c20.x + r0.y*c20.y + r0.z*c20.z + r0.w*c20.w
         + r1.x*c21.x + r1.y*c21.y + r1.z*c21.z + r1.w*c21.w;
      a2 = r0.x*c30.x + r0.y*c30.y + r0.z*c30.z + r0.w*c30.w
         + r1.x*c31.x + r1.y*c31.y + r1.z*c31.z + r1.w*c31.w;
      a3 = r0.x*c40.x + r0.y*c40.y + r0.z*c40.z + r0.w*c40.w
         + r1.x*c41.x + r1.y*c41.y + r1.z*c41.z + r1.w*c41.w;
    }
#pragma unroll
    for (int off = 32; off; off >>= 1) {
      a0 += __shfl_down(a0, off); a1 += __shfl_down(a1, off);
      a2 += __shfl_down(a2, off); a3 += __shfl_down(a3, off);
    }
    const int wv = threadIdx.x >> 6;
    if ((threadIdx.x & 63) == 0) {
      red[wv][0] = a0; red[wv][1] = a1; red[wv][2] = a2; red[wv][3] = a3;
    }
    __syncthreads();
    if (threadIdx.x < 4) {
      const float v = red[0][threadIdx.x] + red[1][threadIdx.x] +
                      red[2][threadIdx.x] + red[3][threadIdx.x];
      ENb[(size_t)threadIdx.x * 768 + e] = (e < 691) ? v : 0.f;
    }
  }
}

// ---------------------------------------------------------------------------
// combine1: bids [0,7680)  h1 = relu(b1_s + sum_t (H0h0+H0h1)[P[c][t]])
//           bids [7680,9216) W2EN = W2ENh0 + W2ENh1
// ---------------------------------------------------------------------------
__global__ __launch_bounds__(128) void combine1_k(const unsigned short* __restrict__ H0h,
                                                  unsigned short* __restrict__ h1,
                                                  const float* __restrict__ b11,
                                                  const float* __restrict__ b12,
                                                  const float* __restrict__ b13,
                                                  const float* __restrict__ b14,
                                                  const unsigned short* __restrict__ W2ENh,
                                                  unsigned short* __restrict__ W2EN) {
  const int bid = blockIdx.x;
  if (bid < 7680) {
    const int cb = bid;                  // c*512+b
    const int c = cb >> 9, b = cb & 511;
    const int s = (c < 4) ? 1 : (c < 10) ? 2 : (c < 14) ? 3 : 4;
    const unsigned char P[15][4] = {
      {0,0,0,0},{1,0,0,0},{2,0,0,0},{3,0,0,0},
      {4,7,0,0},{4,8,0,0},{4,9,0,0},{5,8,0,0},{5,9,0,0},{6,9,0,0},
      {10,12,14,0},{10,12,15,0},{10,13,15,0},{11,13,15,0},
      {16,17,18,19}};
    const float* b1 = (s == 1) ? b11 : (s == 2) ? b12 : (s == 3) ? b13 : b14;
    const int o = threadIdx.x << 2;
    float4 a = *(const float4*)(b1 + o);
    for (int t = 0; t < s; ++t) {
      const int p = P[c][t];
      const size_t base = ((size_t)(p * 512 + b)) * 512 + o;
      const ushort4 h0 = *(const ushort4*)(H0h + base);
      const ushort4 h1v = *(const ushort4*)(H0h + 5242880 + base);
      a.x += bf2f(h0.x) + bf2f(h1v.x); a.y += bf2f(h0.y) + bf2f(h1v.y);
      a.z += bf2f(h0.z) + bf2f(h1v.z); a.w += bf2f(h0.w) + bf2f(h1v.w);
    }
    ushort4 ov;
    ov.x = f2bf(fmaxf(a.x, 0.f)); ov.y = f2bf(fmaxf(a.y, 0.f));
    ov.z = f2bf(fmaxf(a.z, 0.f)); ov.w = f2bf(fmaxf(a.w, 0.f));
    *(ushort4*)(h1 + (size_t)cb * 512 + o) = ov;
  } else {
    const int idx = bid - 7680;          // 0..1535, 1024 shorts per block
    const size_t off = (size_t)idx * 1024 + (size_t)threadIdx.x * 8;
    const bf16x8 a0 = *(const bf16x8*)(W2ENh + off);
    const bf16x8 a1 = *(const bf16x8*)(W2ENh + 1572864 + off);
    bf16x8 ov;
#pragma unroll
    for (int i = 0; i < 8; ++i)
      ov[i] = (short)f2bf(bf2f((unsigned short)a0[i]) + bf2f((unsigned short)a1[i]));
    *(bf16x8*)(W2EN + off) = ov;
  }
}

// combine2 (round-5 proven)
__global__ __launch_bounds__(256) void combine2_k(const float* __restrict__ EN0,
                                                  const float* __restrict__ b_emb,
                                                  const float* __restrict__ b_node,
                                                  float* __restrict__ out0,
                                                  float* __restrict__ out1) {
  const int b   = blockIdx.x;
  const int col = blockIdx.y * 256 + threadIdx.x;
  if (col >= 691) return;
  float vals[15];
#pragma unroll
  for (int j = 0; j < 15; ++j)
    vals[j] = EN0[((size_t)(j * 512 + b)) * 768 + col];
  const int MSK[15] = {1,2,4,8,3,5,9,6,10,12,7,11,13,14,15};
  if (col < 300) {
    const float be = b_emb[col];
#pragma unroll
    for (int i = 0; i < 15; ++i) {
      float sum = be;
#pragma unroll
      for (int j = 0; j < 15; ++j)
        if ((MSK[j] & MSK[i]) == MSK[j]) sum += vals[j];
      out0[((size_t)b * 15 + i) * 300 + col] = sum;
    }
  } else {
    const int v = col - 300;
    const float bn = b_node[v];
#pragma unroll
    for (int i = 0; i < 15; ++i) {
      float sum = bn;
#pragma unroll
      for (int j = 0; j < 15; ++j)
        if ((MSK[j] & MSK[i]) == MSK[j]) sum += vals[j];
      out1[((size_t)b * 391 + v) * 15 + i] = sum;
    }
  }
}

// ---------------------------------------------------------------------------
extern "C" void kernel_launch(void* const* d_in, const int* in_sizes, int n_in,
                              void* d_out, int out_size, void* d_ws, size_t ws_size,
                              hipStream_t stream) {
  const float* x     = (const float*)d_in[0];
  const float* w11   = (const float*)d_in[1];
  const float* b11   = (const float*)d_in[2];
  const float* w21   = (const float*)d_in[3];
  const float* b21   = (const float*)d_in[4];
  const float* w12   = (const float*)d_in[5];
  const float* b12   = (const float*)d_in[6];
  const float* w22   = (const float*)d_in[7];
  const float* b22   = (const float*)d_in[8];
  const float* w13   = (const float*)d_in[9];
  const float* b13   = (const float*)d_in[10];
  const float* w23   = (const float*)d_in[11];
  const float* b23   = (const float*)d_in[12];
  const float* w14   = (const float*)d_in[13];
  const float* b14   = (const float*)d_in[14];
  const float* w24   = (const float*)d_in[15];
  const float* b24   = (const float*)d_in[16];
  const float* wemb  = (const float*)d_in[17];
  const float* bemb  = (const float*)d_in[18];
  const float* wnode = (const float*)d_in[19];
  const float* bnode = (const float*)d_in[20];

  char* ws = (char*)d_ws;
  // r6-proven layout (peak ~79.2 MB); EN0 aliases xrb/w1cat (dead after mega1)
  unsigned short* xrb   = (unsigned short*)(ws + 0);                 //  8,388,608
  unsigned short* w1cat = (unsigned short*)(ws + 8388608);           // -> 29,360,128
  unsigned short* w2t   = (unsigned short*)(ws + 29360128);          // -> 37,748,736
  unsigned short* wen   = (unsigned short*)(ws + 37748736);          // -> 40,894,464
  unsigned short* H0h   = (unsigned short*)(ws + 40894464);          // 2x10,485,760 -> 61,865,984
  unsigned short* W2ENh = (unsigned short*)(ws + 61865984);          // 2x 3,145,728 -> 68,157,440
  unsigned short* W2EN  = (unsigned short*)(ws + 68157440);          // -> 71,303,168
  float*          ENb   = (float*)(ws + 71303168);                   // -> 71,315,456
  unsigned short* h1bf  = (unsigned short*)(ws + 71315456);          // -> 79,179,776
  float*          EN0   = (float*)(ws + 0);                          // 23,592,960

  float* out0 = (float*)d_out;            // embeddings (512,15,300)
  float* out1 = out0 + 2304000;           // node_out^T (512,391,15)

  prep_all_k<<<17664, 256, 0, stream>>>(x, w11, w12, w13, w14, w21, w22, w23, w24,
                                        wemb, wnode, b21, b22, b23, b24,
                                        xrb, w1cat, w2t, wen, ENb);
  mega1_k   <<<208, 512, 0, stream>>>(xrb, w1cat, wen, w2t, H0h, W2ENh);
  combine1_k<<<9216, 128, 0, stream>>>(H0h, h1bf, b11, b12, b13, b14, W2ENh, W2EN);
  gemmF_k   <<<dim3(6, 30), 512, 0, stream>>>(h1bf, W2EN, ENb, EN0);
  combine2_k<<<dim3(512, 3), 256, 0, stream>>>(EN0, bemb, bnode, out0, out1);
}

// Round 20
// 91.366 us; speedup vs baseline: 1.0484x; 1.0484x over previous
//
#include <hip/hip_runtime.h>
#include <stdint.h>

using bf16x8 = __attribute__((ext_vector_type(8))) short;
using f32x4  = __attribute__((ext_vector_type(4))) float;

#define DEVINL __device__ __forceinline__

DEVINL unsigned short f2bf(float f) {
  union { float f; unsigned u; } v; v.f = f;
  unsigned u = v.u;
  return (unsigned short)((u + 0x7FFFu + ((u >> 16) & 1u)) >> 16);
}
DEVINL float bf2f(unsigned short h) {
  union { unsigned u; float f; } v; v.u = ((unsigned)h) << 16;
  return v.f;
}

DEVINL void gload_lds16(const void* g, void* l) {
  __builtin_amdgcn_global_load_lds(
      (const __attribute__((address_space(1))) void*)g,
      (__attribute__((address_space(3))) void*)l, 16, 0, 0);
}

// ---------------------------------------------------------------------------
// r15 core (proven: mega1 43.0 µs): 256x128 bf16 tile, 8 waves (4M x 2N),
// BK=64, 3-slot tile ring (144 KB LDS). Per K-tile 2 phases, each:
// {8 ds_read ; STAGE half (3 gloads) ; [vmcnt(6) ph2 only] ; barrier ;
//  setprio(1) 16 MFMA setprio(0) ; barrier}. T2 XOR swizzle via pre-swizzled
// GLOBAL source (LDS dest linear; bank conflicts measured 0).
// ---------------------------------------------------------------------------
template<int OUT_BF16, int HAS_BIAS>
DEVINL void gemm_core(const unsigned short* __restrict__ A,
                      const unsigned short* __restrict__ B,
                      void* __restrict__ C,
                      const float* __restrict__ bias,
                      int K, int Cld, int arow0, int brow0, int crow0, int ccol0)
{
  __shared__ __align__(16) unsigned short As[3][256 * 64];   // 96 KB
  __shared__ __align__(16) unsigned short Bs[3][128 * 64];   // 48 KB

  const int t    = threadIdx.x;        // 0..511
  const int wave = t >> 6;             // 0..7
  const int lane = t & 63;
  const int wr   = (wave >> 1) << 6;   // 0,64,128,192
  const int wc   = (wave & 1) << 6;    // 0,64
  const int lrow = lane & 15;
  const int kg   = lane >> 4;          // 0..3

  f32x4 acc[4][4];
#pragma unroll
  for (int r = 0; r < 4; ++r)
#pragma unroll
    for (int q = 0; q < 4; ++q) acc[r][q] = (f32x4){0.f, 0.f, 0.f, 0.f};

  // staging (pre-swizzled global source chunk: chunk_phys = chunk ^ (row&7))
  const int srow = t >> 3;                                  // 0..63
  const int scol = (((t & 7) ^ (srow & 7)) << 3);
  const unsigned short* aSrc = A + (size_t)(arow0 + srow) * K + scol;
  const unsigned short* bSrc = B + (size_t)(brow0 + srow) * K + scol;

  // S0 = A rows [0,128) + B rows [0,64); S1 = A rows [128,256) + B rows [64,128)
  auto STAGE_S0 = [&](int slot, int kt) {
    const int k0 = kt << 6;
    char* aD = (char*)As[slot] + wave * 1024;
    char* bD = (char*)Bs[slot] + wave * 1024;
    gload_lds16(aSrc + (size_t)0 * K + k0, aD);
    gload_lds16(aSrc + (size_t)64 * K + k0, aD + 8192);
    gload_lds16(bSrc + (size_t)0 * K + k0, bD);
  };
  auto STAGE_S1 = [&](int slot, int kt) {
    const int k0 = kt << 6;
    char* aD = (char*)As[slot] + wave * 1024;
    char* bD = (char*)Bs[slot] + wave * 1024;
    gload_lds16(aSrc + (size_t)128 * K + k0, aD + 16384);
    gload_lds16(aSrc + (size_t)192 * K + k0, aD + 24576);
    gload_lds16(bSrc + (size_t)64 * K + k0, bD + 8192);
  };

  const int nt = K >> 6;               // >= 8 at all call sites
  STAGE_S0(0, 0); STAGE_S1(0, 0);
  if (nt > 1) { STAGE_S0(1, 1); STAGE_S1(1, 1); }

  // swizzled read chunk offsets: chunk = (kg + kk/8) ^ (row&7)
  const int rs = lrow & 7;
  const int cA0 = ((kg + 0) ^ rs) << 3;   // kk = 0
  const int cA1 = ((kg + 4) ^ rs) << 3;   // kk = 32

  // validate tile 0 before first reads
  if (nt > 1) { asm volatile("s_waitcnt vmcnt(6)" ::: "memory"); }
  else        { asm volatile("s_waitcnt vmcnt(0)" ::: "memory"); }
  __builtin_amdgcn_s_barrier();

  int sl = 0;                          // slot of tile kt
  for (int kt = 0; kt < nt; ++kt) {
    const unsigned short* Ab = As[sl];
    const unsigned short* Bb = Bs[sl];
    int s2 = sl + 2; if (s2 >= 3) s2 -= 3;   // slot for kt+2

    // ---------- phase 1: reads kk=0 ; stage S0(kt+2) ; bar ; MFMA ; bar
    bf16x8 af[4], bq[4];
#pragma unroll
    for (int r = 0; r < 4; ++r)
      af[r] = *(const bf16x8*)&Ab[(wr + r * 16 + lrow) * 64 + cA0];
#pragma unroll
    for (int q = 0; q < 4; ++q)
      bq[q] = *(const bf16x8*)&Bb[(wc + q * 16 + lrow) * 64 + cA0];
    if (kt + 2 < nt) STAGE_S0(s2, kt + 2);
    __builtin_amdgcn_s_barrier();
    __builtin_amdgcn_s_setprio(1);
#pragma unroll
    for (int r = 0; r < 4; ++r)
#pragma unroll
      for (int q = 0; q < 4; ++q)
        acc[r][q] = __builtin_amdgcn_mfma_f32_16x16x32_bf16(af[r], bq[q], acc[r][q], 0, 0, 0);
    __builtin_amdgcn_s_setprio(0);
    __builtin_amdgcn_s_barrier();

    // ---------- phase 2: reads kk=32 ; stage S1(kt+2) ; vmcnt ; bar ; MFMA ; bar
#pragma unroll
    for (int r = 0; r < 4; ++r)
      af[r] = *(const bf16x8*)&Ab[(wr + r * 16 + lrow) * 64 + cA1];
#pragma unroll
    for (int q = 0; q < 4; ++q)
      bq[q] = *(const bf16x8*)&Bb[(wc + q * 16 + lrow) * 64 + cA1];
    if (kt + 2 < nt) {
      STAGE_S1(s2, kt + 2);
      asm volatile("s_waitcnt vmcnt(6)" ::: "memory");   // kt+1 landed; kt+2 in flight
    } else if (kt + 1 < nt) {
      asm volatile("s_waitcnt vmcnt(0)" ::: "memory");   // drain kt+1 (tail)
    }
    __builtin_amdgcn_s_barrier();
    __builtin_amdgcn_s_setprio(1);
#pragma unroll
    for (int r = 0; r < 4; ++r)
#pragma unroll
      for (int q = 0; q < 4; ++q)
        acc[r][q] = __builtin_amdgcn_mfma_f32_16x16x32_bf16(af[r], bq[q], acc[r][q], 0, 0, 0);
    __builtin_amdgcn_s_setprio(0);
    __builtin_amdgcn_s_barrier();

    ++sl; if (sl == 3) sl = 0;
  }

  // epilogue: C/D layout col=lane&15, row=(lane>>4)*4+v  [m89/m91 verified]
#pragma unroll
  for (int r = 0; r < 4; ++r) {
#pragma unroll
    for (int q = 0; q < 4; ++q) {
      const int col = ccol0 + wc + q * 16 + lrow;
      const float bv = HAS_BIAS ? bias[col] : 0.f;
#pragma unroll
      for (int v = 0; v < 4; ++v) {
        const int row = crow0 + wr + r * 16 + (kg << 2) + v;
        const float val = acc[r][q][v] + bv;
        if (OUT_BF16)
          ((unsigned short*)C)[(size_t)row * Cld + col] = f2bf(val);
        else
          ((float*)C)[(size_t)row * Cld + col] = val;
      }
    }
  }
}

// ---------------------------------------------------------------------------
// mega1 (208 blocks x 512 thr) — r15 exact.
// ---------------------------------------------------------------------------
__global__ __launch_bounds__(512) void mega1_k(const unsigned short* __restrict__ xrb,
                                               const unsigned short* __restrict__ w1cat,
                                               const unsigned short* __restrict__ wen,
                                               const unsigned short* __restrict__ w2t,
                                               unsigned short* __restrict__ H0p,
                                               unsigned short* __restrict__ W2EN) {
  const int bid = blockIdx.x;
  if (bid < 160) {
    const int p = bid >> 3, q = bid & 7;
    const int rt = q >> 2, ct = q & 3;
    const int MM[20] = {0,1,2,3, 0,1,2, 1,2,3, 0,1, 1,2, 2,3, 0,1,2,3};
    const int JJ[20] = {0,0,0,0, 1,1,1, 2,2,2, 3,3, 4,4, 5,5, 6,7,8,9};
    gemm_core<1, 0>(xrb, w1cat, H0p, nullptr, 2048, 512,
                    MM[p] * 512 + rt * 256, JJ[p] * 512 + ct * 128,
                    p * 512 + rt * 256, ct * 128);
  } else {
    const int b2 = bid - 160;
    const int s = b2 / 12, r = b2 % 12;
    const int rt = r >> 2, ct = r & 3;
    gemm_core<1, 0>(wen, w2t, W2EN, nullptr, 2048, 512,
                    rt * 256, s * 512 + ct * 128,
                    s * 768 + rt * 256, ct * 128);
  }
}

// gemmF: EN0 = h1(7680x512) @ W2EN_s^T + ENb_s  -> bf16 out (was fp32; halves
// WRITE traffic 23.6->11.8 MB, and combine2's reads likewise)
__global__ __launch_bounds__(512) void gemmF_k(const unsigned short* __restrict__ h1,
                                               const unsigned short* __restrict__ W2EN,
                                               const float* __restrict__ ENb,
                                               unsigned short* __restrict__ EN0) {
  const int y = blockIdx.y;                  // 0..29 row tiles of 256
  const int c = y >> 1;
  const int s = (c < 4) ? 1 : (c < 10) ? 2 : (c < 14) ? 3 : 4;
  gemm_core<1, 1>(h1, W2EN, EN0, ENb + (size_t)(s - 1) * 768, 512, 768,
                  y * 256, (s - 1) * 768 + blockIdx.x * 128,
                  y * 256, blockIdx.x * 128);
}

// ---------------------------------------------------------------------------
// prep_all (r13 proven): 5 prep bodies in one dispatch (17664 blocks).
// ---------------------------------------------------------------------------
__global__ __launch_bounds__(256) void prep_all_k(const float* __restrict__ x,
                                                  const float* w11, const float* w12,
                                                  const float* w13, const float* w14,
                                                  const float* w21, const float* w22,
                                                  const float* w23, const float* w24,
                                                  const float* __restrict__ wemb,
                                                  const float* __restrict__ wnode,
                                                  const float* b21, const float* b22,
                                                  const float* b23, const float* b24,
                                                  unsigned short* __restrict__ xrb,
                                                  unsigned short* __restrict__ w1cat,
                                                  unsigned short* __restrict__ w2t,
                                                  unsigned short* __restrict__ wen,
                                                  float* __restrict__ ENb) {
  __shared__ float lds[64][65];
  __shared__ float red[4][4];
  const int bid = blockIdx.x;
  if (bid < 10240) {                    // ---- w1cat
    const int tid = bid * 256 + threadIdx.x;
    const int r = tid >> 9;
    const int k = (tid & 511) << 2;
    const int j = r >> 9, o = r & 511;
    const float* src; int s, tt;
    if (j == 0)      { src = w11; s = 1; tt = 0; }
    else if (j < 3)  { src = w12; s = 2; tt = j - 1; }
    else if (j < 6)  { src = w13; s = 3; tt = j - 3; }
    else             { src = w14; s = 4; tt = j - 6; }
    const float4 vv = *(const float4*)(src + (size_t)o * (s * 2048) + tt * 2048 + k);
    ushort4 ov;
    ov.x = f2bf(vv.x); ov.y = f2bf(vv.y); ov.z = f2bf(vv.z); ov.w = f2bf(vv.w);
    *(ushort4*)(w1cat + (size_t)r * 2048 + k) = ov;
  } else if (bid < 14336) {             // ---- xr
    const int tid = (bid - 10240) * 256 + threadIdx.x;
    const int r = tid >> 9;
    const int k = (tid & 511) << 2;
    const int m = r >> 9, b = r & 511;
    const float4 vv = *(const float4*)(x + ((size_t)(b * 4 + m)) * 2048 + k);
    ushort4 o;
    o.x = f2bf(fmaxf(vv.x, 0.f)); o.y = f2bf(fmaxf(vv.y, 0.f));
    o.z = f2bf(fmaxf(vv.z, 0.f)); o.w = f2bf(fmaxf(vv.w, 0.f));
    *(ushort4*)(xrb + (size_t)r * 2048 + k) = o;
  } else if (bid < 15360) {             // ---- w2t
    const int idx = bid - 14336;
    const int s = idx >> 8, rem = idx & 255;
    const int rt = rem >> 3, ct = rem & 7;
    const float* src = (s == 0) ? w21 : (s == 1) ? w22 : (s == 2) ? w23 : w24;
    const int tr = threadIdx.x >> 4;
    const int tc = (threadIdx.x & 15) << 2;
#pragma unroll
    for (int i = 0; i < 4; ++i) {
      const float4 v = *(const float4*)(src + (size_t)(rt * 64 + tr + 16 * i) * 512 + ct * 64 + tc);
      lds[tr + 16 * i][tc + 0] = v.x; lds[tr + 16 * i][tc + 1] = v.y;
      lds[tr + 16 * i][tc + 2] = v.z; lds[tr + 16 * i][tc + 3] = v.w;
    }
    __syncthreads();
#pragma unroll
    for (int i = 0; i < 4; ++i) {
      ushort4 ov;
      ov.x = f2bf(lds[tc + 0][tr + 16 * i]); ov.y = f2bf(lds[tc + 1][tr + 16 * i]);
      ov.z = f2bf(lds[tc + 2][tr + 16 * i]); ov.w = f2bf(lds[tc + 3][tr + 16 * i]);
      *(ushort4*)(w2t + ((size_t)s * 512 + ct * 64 + tr + 16 * i) * 2048 + rt * 64 + tc) = ov;
    }
  } else if (bid < 16896) {             // ---- wen
    const int tid = (bid - 15360) * 256 + threadIdx.x;
    const int r = tid >> 9;
    const int k = (tid & 511) << 2;
    float4 vv = make_float4(0.f, 0.f, 0.f, 0.f);
    if (r < 300)       vv = *(const float4*)(wemb + (size_t)r * 2048 + k);
    else if (r < 691)  vv = *(const float4*)(wnode + (size_t)(r - 300) * 2048 + k);
    ushort4 ov;
    ov.x = f2bf(vv.x); ov.y = f2bf(vv.y); ov.z = f2bf(vv.z); ov.w = f2bf(vv.w);
    *(ushort4*)(wen + (size_t)r * 2048 + k) = ov;
  } else {                              // ---- enb v2
    const int e = bid - 16896;          // 0..767
    const int t8 = threadIdx.x << 3;
    float a0 = 0.f, a1 = 0.f, a2 = 0.f, a3 = 0.f;
    if (e < 691) {
      const float* row = (e < 300) ? (wemb + (size_t)e * 2048)
                                   : (wnode + (size_t)(e - 300) * 2048);
      const float4 r0 = *(const float4*)(row + t8);
      const float4 r1 = *(const float4*)(row + t8 + 4);
      const float4 c10 = *(const float4*)(b21 + t8), c11 = *(const float4*)(b21 + t8 + 4);
      const float4 c20 = *(const float4*)(b22 + t8), c21 = *(const float4*)(b22 + t8 + 4);
      const float4 c30 = *(const float4*)(b23 + t8), c31 = *(const float4*)(b23 + t8 + 4);
      const float4 c40 = *(const float4*)(b24 + t8), c41 = *(const float4*)(b24 + t8 + 4);
      a0 = r0.x*c10.x + r0.y*c10.y + r0.z*c10.z + r0.w*c10.w
         + r1.x*c11.x + r1.y*c11.y + r1.z*c11.z + r1.w*c11.w;
      a1 = r0.x*c20.x + r0.y*c20.y + r0.z*c20.z + r0.w*c20.w
         + r1.x*c21.x + r1.y*c21.y + r1.z*c21.z + r1.w*c21.w;
      a2 = r0.x*c30.x + r0.y*c30.y + r0.z*c30.z + r0.w*c30.w
         + r1.x*c31.x + r1.y*c31.y + r1.z*c31.z + r1.w*c31.w;
      a3 = r0.x*c40.x + r0.y*c40.y + r0.z*c40.z + r0.w*c40.w
         + r1.x*c41.x + r1.y*c41.y + r1.z*c41.z + r1.w*c41.w;
    }
#pragma unroll
    for (int off = 32; off; off >>= 1) {
      a0 += __shfl_down(a0, off); a1 += __shfl_down(a1, off);
      a2 += __shfl_down(a2, off); a3 += __shfl_down(a3, off);
    }
    const int wv = threadIdx.x >> 6;
    if ((threadIdx.x & 63) == 0) {
      red[wv][0] = a0; red[wv][1] = a1; red[wv][2] = a2; red[wv][3] = a3;
    }
    __syncthreads();
    if (threadIdx.x < 4) {
      const float v = red[0][threadIdx.x] + red[1][threadIdx.x] +
                      red[2][threadIdx.x] + red[3][threadIdx.x];
      ENb[(size_t)threadIdx.x * 768 + e] = (e < 691) ? v : 0.f;
    }
  }
}

// combine1 (round-5 proven)
__global__ __launch_bounds__(128) void combine1_k(const unsigned short* __restrict__ H0p,
                                                  unsigned short* __restrict__ h1,
                                                  const float* __restrict__ b11,
                                                  const float* __restrict__ b12,
                                                  const float* __restrict__ b13,
                                                  const float* __restrict__ b14) {
  const int cb = blockIdx.x;            // 0..7679 = c*512+b
  const int c = cb >> 9, b = cb & 511;
  const int s = (c < 4) ? 1 : (c < 10) ? 2 : (c < 14) ? 3 : 4;
  const unsigned char P[15][4] = {
    {0,0,0,0},{1,0,0,0},{2,0,0,0},{3,0,0,0},
    {4,7,0,0},{4,8,0,0},{4,9,0,0},{5,8,0,0},{5,9,0,0},{6,9,0,0},
    {10,12,14,0},{10,12,15,0},{10,13,15,0},{11,13,15,0},
    {16,17,18,19}};
  const float* b1 = (s == 1) ? b11 : (s == 2) ? b12 : (s == 3) ? b13 : b14;
  const int o = threadIdx.x << 2;
  float4 a = *(const float4*)(b1 + o);
  for (int t = 0; t < s; ++t) {
    const int p = P[c][t];
    const ushort4 hv = *(const ushort4*)(H0p + ((size_t)(p * 512 + b)) * 512 + o);
    a.x += bf2f(hv.x); a.y += bf2f(hv.y); a.z += bf2f(hv.z); a.w += bf2f(hv.w);
  }
  ushort4 ov;
  ov.x = f2bf(fmaxf(a.x, 0.f)); ov.y = f2bf(fmaxf(a.y, 0.f));
  ov.z = f2bf(fmaxf(a.z, 0.f)); ov.w = f2bf(fmaxf(a.w, 0.f));
  *(ushort4*)(h1 + (size_t)cb * 512 + o) = ov;
}

// combine2 (round-5 structure, bf16 EN0 reads)
__global__ __launch_bounds__(256) void combine2_k(const unsigned short* __restrict__ EN0,
                                                  const float* __restrict__ b_emb,
                                                  const float* __restrict__ b_node,
                                                  float* __restrict__ out0,
                                                  float* __restrict__ out1) {
  const int b   = blockIdx.x;
  const int col = blockIdx.y * 256 + threadIdx.x;
  if (col >= 691) return;
  float vals[15];
#pragma unroll
  for (int j = 0; j < 15; ++j)
    vals[j] = bf2f(EN0[((size_t)(j * 512 + b)) * 768 + col]);
  const int MSK[15] = {1,2,4,8,3,5,9,6,10,12,7,11,13,14,15};
  if (col < 300) {
    const float be = b_emb[col];
#pragma unroll
    for (int i = 0; i < 15; ++i) {
      float sum = be;
#pragma unroll
      for (int j = 0; j < 15; ++j)
        if ((MSK[j] & MSK[i]) == MSK[j]) sum += vals[j];
      out0[((size_t)b * 15 + i) * 300 + col] = sum;
    }
  } else {
    const int v = col - 300;
    const float bn = b_node[v];
#pragma unroll
    for (int i = 0; i < 15; ++i) {
      float sum = bn;
#pragma unroll
      for (int j = 0; j < 15; ++j)
        if ((MSK[j] & MSK[i]) == MSK[j]) sum += vals[j];
      out1[((size_t)b * 391 + v) * 15 + i] = sum;
    }
  }
}

// ---------------------------------------------------------------------------
extern "C" void kernel_launch(void* const* d_in, const int* in_sizes, int n_in,
                              void* d_out, int out_size, void* d_ws, size_t ws_size,
                              hipStream_t stream) {
  const float* x     = (const float*)d_in[0];
  const float* w11   = (const float*)d_in[1];
  const float* b11   = (const float*)d_in[2];
  const float* w21   = (const float*)d_in[3];
  const float* b21   = (const float*)d_in[4];
  const float* w12   = (const float*)d_in[5];
  const float* b12   = (const float*)d_in[6];
  const float* w22   = (const float*)d_in[7];
  const float* b22   = (const float*)d_in[8];
  const float* w13   = (const float*)d_in[9];
  const float* b13   = (const float*)d_in[10];
  const float* w23   = (const float*)d_in[11];
  const float* b23   = (const float*)d_in[12];
  const float* w14   = (const float*)d_in[13];
  const float* b14   = (const float*)d_in[14];
  const float* w24   = (const float*)d_in[15];
  const float* b24   = (const float*)d_in[16];
  const float* wemb  = (const float*)d_in[17];
  const float* bemb  = (const float*)d_in[18];
  const float* wnode = (const float*)d_in[19];
  const float* bnode = (const float*)d_in[20];

  char* ws = (char*)d_ws;
  unsigned short* xrb   = (unsigned short*)(ws + 0);                 //  8,388,608
  unsigned short* w1cat = (unsigned short*)(ws + 8388608);           // -> 29,360,128
  unsigned short* w2t   = (unsigned short*)(ws + 29360128);          // -> 37,748,736
  unsigned short* wen   = (unsigned short*)(ws + 37748736);          // -> 40,894,464
  unsigned short* H0p   = (unsigned short*)(ws + 40894464);          // -> 51,380,224
  unsigned short* W2EN  = (unsigned short*)(ws + 51380224);          // -> 54,525,952
  float*          ENb   = (float*)(ws + 54525952);                   // -> 54,538,240
  unsigned short* h1bf  = (unsigned short*)(ws + 54538240);          // -> 62,402,560
  unsigned short* EN0   = (unsigned short*)(ws + 0);                 // 11,796,480 (aliases xrb)

  float* out0 = (float*)d_out;            // embeddings (512,15,300)
  float* out1 = out0 + 2304000;           // node_out^T (512,391,15)

  prep_all_k<<<17664, 256, 0, stream>>>(x, w11, w12, w13, w14, w21, w22, w23, w24,
                                        wemb, wnode, b21, b22, b23, b24,
                                        xrb, w1cat, w2t, wen, ENb);
  mega1_k   <<<208, 512, 0, stream>>>(xrb, w1cat, wen, w2t, H0p, W2EN);
  combine1_k<<<7680, 128, 0, stream>>>(H0p, h1bf, b11, b12, b13, b14);
  gemmF_k   <<<dim3(6, 30), 512, 0, stream>>>(h1bf, W2EN, ENb, EN0);
  combine2_k<<<dim3(512, 3), 256, 0, stream>>>(EN0, bemb, bnode, out0, out1);
}